// Round 1
// baseline (286.326 us; speedup 1.0000x reference)
//
#include <hip/hip_runtime.h>
#include <math.h>

// Problem constants (fixed by the reference):
//   x:    [B=8, C=4, H=256, W=256] f32
//   filt: [B, C*K*K=100, H, W]     f32
//   out:  [B, 1, H, W]             f32
//   out[b,h,w] = tanh( sum_{c,p} x_pad[b,c,h+p/5-2, w+p%5-2] * filt[b,c*25+p,h,w] )
#define Hd 256
#define Wd 256
#define Cc 4
#define Kk 5

__global__ __launch_bounds__(256) void dynf_kernel(const float* __restrict__ x,
                                                   const float* __restrict__ filt,
                                                   float* __restrict__ out) {
    // One thread = 4 consecutive w-pixels (float4 granularity).
    // Wave (64 lanes) = one full row: lane = w-group, (h,b) wave-uniform.
    int t  = blockIdx.x * blockDim.x + threadIdx.x;   // [0, 8*256*64)
    int w4 = t & 63;
    int h  = (t >> 6) & 255;
    int b  = t >> 14;
    int w0 = w4 << 2;

    const size_t HW = (size_t)Hd * Wd;
    const float* xb = x + (size_t)b * Cc * HW;
    const float* fb = filt + (size_t)b * (Cc * Kk * Kk) * HW;

    float acc0 = 0.f, acc1 = 0.f, acc2 = 0.f, acc3 = 0.f;

    for (int c = 0; c < Cc; ++c) {
        const float* xc = xb + (size_t)c * HW;
        #pragma unroll
        for (int di = 0; di < Kk; ++di) {
            int hh = h + di - 2;
            if (hh < 0 || hh >= Hd) continue;          // wave-uniform: zero-pad rows contribute 0
            const float* xr = xc + (size_t)hh * Wd;

            // x window for 4 pixels: xrow[0..7] = x[hh][w0-2 .. w0+5]
            // covered by 3 aligned float4 loads; only lanes 0 and 63 need zero-fill.
            float4 left  = (w0 >= 4)      ? *(const float4*)(xr + w0 - 4) : make_float4(0.f,0.f,0.f,0.f);
            float4 mid   =                  *(const float4*)(xr + w0);
            float4 right = (w0 + 4 < Wd)  ? *(const float4*)(xr + w0 + 4) : make_float4(0.f,0.f,0.f,0.f);
            float xrow[8];
            xrow[0] = left.z;  xrow[1] = left.w;
            xrow[2] = mid.x;   xrow[3] = mid.y;  xrow[4] = mid.z;  xrow[5] = mid.w;
            xrow[6] = right.x; xrow[7] = right.y;

            const float* fr = fb + ((size_t)(c * (Kk*Kk) + di * Kk)) * HW + (size_t)h * Wd + w0;
            #pragma unroll
            for (int dj = 0; dj < Kk; ++dj) {
                float4 f = *(const float4*)(fr + (size_t)dj * HW);  // coalesced 16B/lane stream
                acc0 = fmaf(xrow[dj + 0], f.x, acc0);
                acc1 = fmaf(xrow[dj + 1], f.y, acc1);
                acc2 = fmaf(xrow[dj + 2], f.z, acc2);
                acc3 = fmaf(xrow[dj + 3], f.w, acc3);
            }
        }
    }

    float4 o;
    o.x = tanhf(acc0); o.y = tanhf(acc1); o.z = tanhf(acc2); o.w = tanhf(acc3);
    *(float4*)(out + (size_t)b * HW + (size_t)h * Wd + w0) = o;
}

extern "C" void kernel_launch(void* const* d_in, const int* in_sizes, int n_in,
                              void* d_out, int out_size, void* d_ws, size_t ws_size,
                              hipStream_t stream) {
    const float* x    = (const float*)d_in[0];   // [8,4,256,256]
    const float* filt = (const float*)d_in[1];   // [8,100,256,256]
    float* out        = (float*)d_out;           // [8,1,256,256]

    const int total_threads = 8 * 256 * 64;      // one thread per 4 pixels
    const int block = 256;
    const int grid  = total_threads / block;     // 512
    dynf_kernel<<<grid, block, 0, stream>>>(x, filt, out);
}

// Round 2
// 274.019 us; speedup vs baseline: 1.0449x; 1.0449x over previous
//
#include <hip/hip_runtime.h>
#include <math.h>

// x:    [B=8, C=4, H=256, W=256] f32
// filt: [B, C*25, H, W]          f32
// out:  [B, 1, H, W]             f32
// out[b,h,w] = tanh( sum_{c,p} x_pad[b,c,h+p/5-2, w+p%5-2] * filt[b,c*25+p,h,w] )
#define Hd 256
#define Wd 256
#define Cc 4
#define KK 5

typedef float v4f __attribute__((ext_vector_type(4)));

__global__ __launch_bounds__(256, 4) void dynf_kernel(const float* __restrict__ x,
                                                      const float* __restrict__ filt,
                                                      float* __restrict__ out) {
    // Block = one (b,h) output row. Wave = one input channel c. Lane = 4-pixel group.
    const int bh   = blockIdx.x;            // [0, 2048)
    const int b    = bh >> 8;
    const int h    = bh & 255;
    const int c    = threadIdx.x >> 6;      // wave id = channel
    const int lane = threadIdx.x & 63;
    const int w0   = lane << 2;

    const size_t HW = (size_t)Hd * Wd;
    const float* xc = x + ((size_t)b * Cc + c) * HW;
    const float* fb = filt + ((size_t)(b * (Cc * KK * KK) + c * (KK * KK))) * HW
                      + (size_t)h * Wd + w0;

    float a0 = 0.f, a1 = 0.f, a2 = 0.f, a3 = 0.f;
    const v4f vzero = {0.f, 0.f, 0.f, 0.f};

    #pragma unroll
    for (int di = 0; di < KK; ++di) {
        const int hh = h + di - 2;
        if (hh >= 0 && hh < Hd) {                 // wave-uniform; skips x AND filt loads (×0 anyway)
            const float* xr = xc + (size_t)hh * Wd;
            // x window [w0-2, w0+5] via 3 aligned float4 loads; edge lanes zero-filled.
            v4f left  = *(const v4f*)(xr + (w0 ? (w0 - 4) : 0));
            v4f mid   = *(const v4f*)(xr + w0);
            v4f right = *(const v4f*)(xr + ((w0 + 4 < Wd) ? (w0 + 4) : 0));
            if (w0 == 0)      left  = vzero;
            if (w0 + 4 >= Wd) right = vzero;
            float xrow[8] = {left.z, left.w, mid.x, mid.y, mid.z, mid.w, right.x, right.y};

            const float* fr = fb + (size_t)(di * KK) * HW;
            #pragma unroll
            for (int dj = 0; dj < KK; ++dj) {
                // nontemporal: filt has zero reuse — don't evict x from L1/L2
                v4f f = __builtin_nontemporal_load((const v4f*)(fr + (size_t)dj * HW));
                a0 = fmaf(xrow[dj + 0], f.x, a0);
                a1 = fmaf(xrow[dj + 1], f.y, a1);
                a2 = fmaf(xrow[dj + 2], f.z, a2);
                a3 = fmaf(xrow[dj + 3], f.w, a3);
            }
        }
    }

    // Reduce the 4 channel-waves through LDS (write/read = consecutive b128, conflict-free).
    __shared__ v4f red[Cc][64];
    v4f acc = {a0, a1, a2, a3};
    red[c][lane] = acc;
    __syncthreads();

    if (c == 0) {
        v4f s = red[0][lane] + red[1][lane] + red[2][lane] + red[3][lane];
        v4f o;
        o.x = tanhf(s.x); o.y = tanhf(s.y); o.z = tanhf(s.z); o.w = tanhf(s.w);
        __builtin_nontemporal_store(o, (v4f*)(out + (size_t)b * HW + (size_t)h * Wd + w0));
    }
}

extern "C" void kernel_launch(void* const* d_in, const int* in_sizes, int n_in,
                              void* d_out, int out_size, void* d_ws, size_t ws_size,
                              hipStream_t stream) {
    const float* x    = (const float*)d_in[0];   // [8,4,256,256]
    const float* filt = (const float*)d_in[1];   // [8,100,256,256]
    float* out        = (float*)d_out;           // [8,1,256,256]

    const int grid  = 8 * 256;   // one block per (b,h) row
    const int block = 256;       // 4 waves = 4 channels
    dynf_kernel<<<grid, block, 0, stream>>>(x, filt, out);
}